// Round 12
// baseline (213.938 us; speedup 1.0000x reference)
//
#include <hip/hip_runtime.h>

typedef __attribute__((ext_vector_type(8))) short bf16x8;
typedef __attribute__((ext_vector_type(4))) float f32x4;
typedef __attribute__((ext_vector_type(16))) float f32x16;
typedef __attribute__((ext_vector_type(4))) short short4v;

namespace {
constexpr int B = 8;
constexpr int N = 1568;
constexpr int NP = 1664;                 // padded rows: 13 q-tiles x 128
constexpr int C = 768;
constexpr int H = 12;
constexpr int D = 64;
constexpr int M = B * N;                 // 12544
constexpr int NT = 25;                   // kv tiles of 64
constexpr int QT = 13;                   // q tiles of 128
constexpr size_t QKP = (size_t)B * H * NP * D;
// ws layout (ushort): xb | Wb | q | k | vT
constexpr size_t OFF_XB = 0;
constexpr size_t OFF_WB = OFF_XB + (size_t)M * C;
constexpr size_t OFF_Q  = OFF_WB + (size_t)3 * C * C;
constexpr size_t OFF_K  = OFF_Q + QKP;
constexpr size_t OFF_VT = OFF_K + QKP;
constexpr float LOG2E = 1.44269504088896f;
}

__device__ __forceinline__ ushort f2bf(float f) {
    union { float f; unsigned u; } a; a.f = f;
    unsigned u = a.u;
    u += 0x7FFF + ((u >> 16) & 1);   // RNE
    return (ushort)(u >> 16);
}
__device__ __forceinline__ void gload16(const ushort* g, ushort* l) {
    __builtin_amdgcn_global_load_lds(
        (const __attribute__((address_space(1))) ushort*)g,
        (__attribute__((address_space(3))) ushort*)l, 16, 0, 0);
}
__device__ __forceinline__ unsigned cvtpk(float lo, float hi) {
    unsigned r;
    asm("v_cvt_pk_bf16_f32 %0, %1, %2" : "=v"(r) : "v"(lo), "v"(hi));
    return r;
}
__device__ __forceinline__ void plswap(unsigned &a, unsigned &b) {
    asm("v_permlane32_swap_b32 %0, %1" : "+v"(a), "+v"(b));
}

// ---------------------------------------------------------------------------
// Prepass: fp32 -> bf16 for x and W.
// ---------------------------------------------------------------------------
__global__ __launch_bounds__(256) void cvt_bf16_kernel(
    const float* __restrict__ x, const float* __restrict__ W,
    ushort* __restrict__ xb, ushort* __restrict__ wb)
{
    constexpr int NX = M * C / 4;
    constexpr int NW = 3 * C * C / 4;
    for (int i = blockIdx.x * blockDim.x + threadIdx.x; i < NX + NW;
         i += gridDim.x * blockDim.x) {
        float4 v; ushort* dst; int o;
        if (i < NX) { v = ((const float4*)x)[i]; dst = xb; o = i; }
        else        { v = ((const float4*)W)[i - NX]; dst = wb; o = i - NX; }
        short4v s;
        s.x = (short)f2bf(v.x); s.y = (short)f2bf(v.y);
        s.z = (short)f2bf(v.z); s.w = (short)f2bf(v.w);
        *(short4v*)(dst + (size_t)o * 4) = s;
    }
}

// ---------------------------------------------------------------------------
// QKV GEMM, bf16 MFMA 128x128 BK=64. ONE operand order for ALL blocks:
// swapped mfma(W-frag, x-frag) -> D[j][m]: col(l15)=m, rows(lg*4+r)=4
// consecutive j. No branch inside the K-loop (round-8 lesson).
// Epilogues (uniform post-loop branch):
//  q/k: norm = 16 reg-FMAs + 2 shfls (xor16,32); 16 packed 8B stores into
//       [bh][n pad][d]  (math bit-identical to the round-9 passing kernel).
//  v:   bias+f2bf -> swizzled LDS T[128][128] (reuses the 32KB staging LDS),
//       barrier, 8 coalesced 16B stores/thread into [bh][d][n pad].
// ---------------------------------------------------------------------------
__global__ __launch_bounds__(256) void qkv_mfma_kernel(
    const ushort* __restrict__ xb, const ushort* __restrict__ Wb,
    const float* __restrict__ bias, ushort* __restrict__ qg,
    ushort* __restrict__ kg, ushort* __restrict__ vtg)
{
    __shared__ __align__(16) ushort SMEM[128 * 128];   // Ab | Bb, reused as T
    ushort* Ab = SMEM;                                  // [128][64]
    ushort* Bb = SMEM + 128 * 64;                       // [128][64]

    const int tid = threadIdx.x;
    const int l = tid & 63;
    const int w = tid >> 6;
    const int l15 = l & 15, lg = l >> 4;

    // bijective XCD swizzle (nwg=1764, q=220, r=4)
    const int orig = blockIdx.x;
    const int xcd = orig & 7;
    const int base = (xcd < 4) ? xcd * 221 : 4 * 221 + (xcd - 4) * 220;
    const int wgid = base + (orig >> 3);
    const int mt = wgid / 18;
    const int jt = wgid - mt * 18;
    const int m0 = mt * 128;
    const int j0 = jt * 128;

    const int wr = w >> 1, wc = w & 1;
    const int Rr = l >> 3;
    const int cch = l & 7;

    f32x4 acc[4][4] = {};

    for (int kb = 0; kb < C; kb += 64) {
        __syncthreads();
        #pragma unroll
        for (int i = 0; i < 4; ++i) {
            const int R = (w * 4 + i) * 8 + Rr;
            const int cg = (cch ^ (R & 7)) * 8;
            gload16(xb + (size_t)(m0 + R) * C + kb + cg, Ab + (w * 4 + i) * 512);
            gload16(Wb + (size_t)(j0 + R) * C + kb + cg, Bb + (w * 4 + i) * 512);
        }
        __syncthreads();

        #pragma unroll
        for (int kk = 0; kk < 2; ++kk) {
            bf16x8 af[4], bfr[4];
            #pragma unroll
            for (int t = 0; t < 4; ++t) {
                const int ra = wr * 64 + t * 16 + l15;
                af[t]  = *(const bf16x8*)&Ab[ra * 64 + ((kk * 4 + lg) ^ (ra & 7)) * 8];
                const int rb = wc * 64 + t * 16 + l15;
                bfr[t] = *(const bf16x8*)&Bb[rb * 64 + ((kk * 4 + lg) ^ (rb & 7)) * 8];
            }
            #pragma unroll
            for (int mi = 0; mi < 4; ++mi)
                #pragma unroll
                for (int nj = 0; nj < 4; ++nj)
                    acc[mi][nj] = __builtin_amdgcn_mfma_f32_16x16x32_bf16(
                        bfr[nj], af[mi], acc[mi][nj], 0, 0, 0);
        }
    }

    const int sel = jt / 6;                  // uniform per block
    const int jbase = j0 + wc * 64;          // one head's 64-col block per wave
    if (sel < 2) {
        // ---- q/k epilogue (round-9 proven) ----
        ushort* dst = (sel == 0) ? qg : kg;
        const float scl = (sel == 0) ? LOG2E : 1.f;
        const int h = (jbase - sel * C) >> 6;
        float4 b4[4];
        #pragma unroll
        for (int nj = 0; nj < 4; ++nj)
            b4[nj] = *(const float4*)&bias[jbase + nj * 16 + lg * 4];
        #pragma unroll
        for (int mi = 0; mi < 4; ++mi) {
            float vals[16];
            float ssq = 0.f;
            #pragma unroll
            for (int nj = 0; nj < 4; ++nj) {
                #pragma unroll
                for (int r = 0; r < 4; ++r) {
                    const float v = acc[mi][nj][r] + ((const float*)&b4[nj])[r];
                    vals[nj * 4 + r] = v;
                    ssq += v * v;
                }
            }
            ssq += __shfl_xor(ssq, 16);
            ssq += __shfl_xor(ssq, 32);
            const float inv = scl / fmaxf(sqrtf(ssq), 1e-12f);
            const int m = m0 + wr * 64 + mi * 16 + l15;
            const int b_ = m / N, n_ = m - b_ * N;
            ushort* o = dst + (((size_t)b_ * H + h) * NP + n_) * D;
            #pragma unroll
            for (int nj = 0; nj < 4; ++nj) {
                short4v s;
                s.x = (short)f2bf(vals[nj * 4 + 0] * inv);
                s.y = (short)f2bf(vals[nj * 4 + 1] * inv);
                s.z = (short)f2bf(vals[nj * 4 + 2] * inv);
                s.w = (short)f2bf(vals[nj * 4 + 3] * inv);
                *(short4v*)(o + nj * 16 + lg * 4) = s;
            }
        }
    } else {
        // ---- v epilogue: LDS transpose (T[j][m], chunk-XOR swizzled) ----
        __syncthreads();   // all waves done reading Ab/Bb
        float4 b4[4];
        #pragma unroll
        for (int nj = 0; nj < 4; ++nj)
            b4[nj] = *(const float4*)&bias[jbase + nj * 16 + lg * 4];
        #pragma unroll
        for (int mi = 0; mi < 4; ++mi) {
            const int m_local = wr * 64 + mi * 16 + l15;
            #pragma unroll
            for (int nj = 0; nj < 4; ++nj) {
                #pragma unroll
                for (int r = 0; r < 4; ++r) {
                    const int j_local = wc * 64 + nj * 16 + lg * 4 + r;
                    const float v = acc[mi][nj][r] + ((const float*)&b4[nj])[r];
                    SMEM[j_local * 128 + (m_local ^ ((j_local & 7) << 3))] = f2bf(v);
                }
            }
        }
        __syncthreads();
        // read out: 2 threads per j row, 64 ushorts each (8 x bf16x8)
        const int j_local = tid >> 1;
        const int mhalf = (tid & 1) * 64;
        const int j = j0 + j_local;
        const int rem = j - 2 * C;
        const int h = rem >> 6, d = rem & 63;
        const int xm = (j_local & 7) << 3;
        #pragma unroll
        for (int c = 0; c < 8; ++c) {
            const int m_chunk = mhalf + c * 8;
            const bf16x8 vv = *(const bf16x8*)&SMEM[j_local * 128 + (m_chunk ^ xm)];
            const int m = m0 + m_chunk;
            const int b_ = m / N, n_ = m - b_ * N;   // 1568 % 8 == 0: chunk stays in one b
            *(bf16x8*)&vtg[(((size_t)b_ * H + h) * D + d) * NP + n_] = vv;
        }
    }
}

// ---------------------------------------------------------------------------
// Cosine attention, swapped-QK^T 32x32x16 + in-register softmax (T12).
// K/V double-buffered in LDS (32 KiB). T14 async-STAGE (round 11, neutral):
// next tile's K/V loaded global->registers at loop top, ds_write'd before
// the barrier. exp2 on pre-scaled scores; setprio around MFMA clusters.
// ---------------------------------------------------------------------------
__global__ __launch_bounds__(256) void attn_kernel(
    const ushort* __restrict__ qg, const ushort* __restrict__ kg,
    const ushort* __restrict__ vtg, float* __restrict__ out)
{
    __shared__ __align__(16) ushort KsB[2][64 * 64];
    __shared__ __align__(16) ushort VtB[2][64 * 64];

    const int tid = threadIdx.x;
    const int l   = tid & 63;
    const int w   = tid >> 6;
    const int l31 = l & 31;
    const int hi  = l >> 5;

    const int bid = blockIdx.x;
    const int grp = bid >> 3;                 // 0..155
    const int qt  = grp % QT;
    const int bh  = (bid & 7) + 8 * (grp / QT);

    const ushort* qp  = qg  + (size_t)bh * NP * D;
    const ushort* kp  = kg  + (size_t)bh * NP * D;
    const ushort* vtp = vtg + (size_t)bh * D * NP;

    const int rsub = l >> 3;
    const int cg   = ((l & 7) ^ rsub) << 3;   // pre-swizzled source chunk

    // ---- Q fragments straight from global (logical d-order) ----
    bf16x8 qf[4];
    {
        const ushort* qr = qp + (size_t)(qt * 128 + w * 32 + l31) * D + hi * 8;
        #pragma unroll
        for (int ds = 0; ds < 4; ++ds)
            qf[ds] = *(const bf16x8*)(qr + ds * 16);
    }

    // ---- prologue DMA: K/V tile 0 ----
    #pragma unroll
    for (int p = 0; p < 2; ++p) {
        const int rb = p * 32 + w * 8;
        gload16(kp + (size_t)(rb + rsub) * D + cg, KsB[0] + rb * 64);
        gload16(vtp + (size_t)(rb + rsub) * NP + cg, VtB[0] + rb * 64);
    }
    __syncthreads();

    f32x16 o_acc[2] = {};
    float denom = 0.f;
    int cur = 0;

    for (int kt = 0; kt < NT; ++kt) {
        // ---- T14 issue-early: next tile's K/V into registers ----
        bf16x8 kst[2], vst[2];
        const bool hasNext = (kt + 1 < NT);
        if (hasNext) {
            #pragma unroll
            for (int p = 0; p < 2; ++p) {
                const int row = p * 32 + w * 8 + rsub;
                kst[p] = *(const bf16x8*)(kp + (size_t)((kt + 1) * 64 + row) * D + cg);
                vst[p] = *(const bf16x8*)(vtp + (size_t)row * NP + (kt + 1) * 64 + cg);
            }
        }
        const ushort* Kc = KsB[cur];
        const ushort* Vc = VtB[cur];

        // ---- S^T = K Q (pre-scaled by log2e), exp2, pack ----
        unsigned pw[16];
        #pragma unroll
        for (int f = 0; f < 2; ++f) {
            if (f == 1 && kt == NT - 1) {
                #pragma unroll
                for (int i = 0; i < 8; ++i) pw[8 + i] = 0;   // pad kv rows
            } else {
                f32x16 st = {};
                __builtin_amdgcn_s_setprio(1);
                #pragma unroll
                for (int ds = 0; ds < 4; ++ds) {
                    const int krow = f * 32 + l31;
                    const int ch = (2 * ds + hi) ^ (krow & 7);
                    const bf16x8 kf = *(const bf16x8*)(Kc + krow * 64 + ch * 8);
                    st = __builtin_amdgcn_mfma_f32_32x32x16_bf16(kf, qf[ds], st, 0, 0, 0);
                }
                __builtin_amdgcn_s_setprio(0);
                float p[16];
                #pragma unroll
                for (int r = 0; r < 16; ++r) p[r] = __builtin_amdgcn_exp2f(st[r]);
                const float t =
                    (((p[0]+p[1])+(p[2]+p[3])) + ((p[4]+p[5])+(p[6]+p[7]))) +
                    (((p[8]+p[9])+(p[10]+p[11])) + ((p[12]+p[13])+(p[14]+p[15])));
                denom += t;
                #pragma unroll
                for (int i = 0; i < 8; ++i)
                    pw[f * 8 + i] = cvtpk(p[2 * i], p[2 * i + 1]);
            }
        }

        // ---- redistribute: words -> PV A-fragments (T12 permlane recipe) ----
        #pragma unroll
        for (int q4 = 0; q4 < 4; ++q4) {
            plswap(pw[q4 * 4 + 0], pw[q4 * 4 + 2]);
            plswap(pw[q4 * 4 + 1], pw[q4 * 4 + 3]);
        }

        // ---- O += P V ----
        __builtin_amdgcn_s_setprio(1);
        #pragma unroll
        for (int dt = 0; dt < 2; ++dt) {
            #pragma unroll
            for (int ks = 0; ks < 4; ++ks) {
                const int vrow = dt * 32 + l31;
                const int ch = (2 * ks + hi) ^ (vrow & 7);
                const bf16x8 vf = *(const bf16x8*)(Vc + vrow * 64 + ch * 8);
                union { unsigned u[4]; bf16x8 v; } A;
                A.u[0] = pw[ks * 4 + 0]; A.u[1] = pw[ks * 4 + 1];
                A.u[2] = pw[ks * 4 + 2]; A.u[3] = pw[ks * 4 + 3];
                o_acc[dt] = __builtin_amdgcn_mfma_f32_32x32x16_bf16(
                    A.v, vf, o_acc[dt], 0, 0, 0);
            }
        }
        __builtin_amdgcn_s_setprio(0);

        // ---- T14 write-late: commit staged K/V to the spare buffer ----
        if (hasNext) {
            ushort* Kn = KsB[cur ^ 1];
            ushort* Vn = VtB[cur ^ 1];
            #pragma unroll
            for (int p = 0; p < 2; ++p) {
                const int rb = p * 32 + w * 8;
                *(bf16x8*)(Kn + rb * 64 + l * 8) = kst[p];
                *(bf16x8*)(Vn + rb * 64 + l * 8) = vst[p];
            }
        }
        __syncthreads();   // orders LDS writes only (no DMA in flight)
        cur ^= 1;
    }

    // ---- epilogue: reduce denom, broadcast via (freed) K LDS ----
    denom += __shfl_xor(denom, 32);
    float* dn = (float*)&KsB[0][0];
    if (hi == 0) dn[w * 32 + l31] = 1.f / denom;
    __syncthreads();

    const int b_ = bh / H;
    const int h_ = bh % H;
    #pragma unroll
    for (int g = 0; g < 4; ++g) {
        const f32x4 inv4 = *(const f32x4*)&dn[w * 32 + g * 8 + hi * 4];
        #pragma unroll
        for (int r3 = 0; r3 < 4; ++r3) {
            const int n = qt * 128 + w * 32 + g * 8 + hi * 4 + r3;
            if (n < N) {
                const float iv = inv4[r3];
                #pragma unroll
                for (int dt = 0; dt < 2; ++dt)
                    out[((size_t)b_ * N + n) * C + (h_ << 6) + dt * 32 + l31] =
                        o_acc[dt][g * 4 + r3] * iv;
            }
        }
    }
}

extern "C" void kernel_launch(void* const* d_in, const int* in_sizes, int n_in,
                              void* d_out, int out_size, void* d_ws, size_t ws_size,
                              hipStream_t stream) {
    const float* x  = (const float*)d_in[0];
    const float* Wq = (const float*)d_in[1];
    const float* bq = (const float*)d_in[2];
    float* out = (float*)d_out;
    ushort* ws = (ushort*)d_ws;

    ushort* xb  = ws + OFF_XB;
    ushort* wb  = ws + OFF_WB;
    ushort* qg  = ws + OFF_Q;
    ushort* kg  = ws + OFF_K;
    ushort* vtg = ws + OFF_VT;

    cvt_bf16_kernel<<<2048, 256, 0, stream>>>(x, Wq, xb, wb);
    qkv_mfma_kernel<<<(M / 128) * (3 * C / 128), 256, 0, stream>>>(xb, wb, bq, qg, kg, vtg);
    attn_kernel<<<QT * B * H, 256, 0, stream>>>(qg, kg, vtg, out);
}

// Round 13
// 175.265 us; speedup vs baseline: 1.2207x; 1.2207x over previous
//
#include <hip/hip_runtime.h>

typedef __attribute__((ext_vector_type(8))) short bf16x8;
typedef __attribute__((ext_vector_type(4))) float f32x4;
typedef __attribute__((ext_vector_type(16))) float f32x16;
typedef __attribute__((ext_vector_type(4))) short short4v;

namespace {
constexpr int B = 8;
constexpr int N = 1568;
constexpr int NP = 1664;                 // padded rows: 13 q-tiles x 128
constexpr int C = 768;
constexpr int H = 12;
constexpr int D = 64;
constexpr int M = B * N;                 // 12544
constexpr int QT = 13;                   // q tiles of 128
constexpr int KT2 = 13;                  // kv tiles of 128 (12 full + tail)
constexpr size_t QKP = (size_t)B * H * NP * D;
// ws layout (ushort): xb | Wb | q | k | vT
constexpr size_t OFF_XB = 0;
constexpr size_t OFF_WB = OFF_XB + (size_t)M * C;
constexpr size_t OFF_Q  = OFF_WB + (size_t)3 * C * C;
constexpr size_t OFF_K  = OFF_Q + QKP;
constexpr size_t OFF_VT = OFF_K + QKP;
constexpr float LOG2E = 1.44269504088896f;
}

__device__ __forceinline__ ushort f2bf(float f) {
    union { float f; unsigned u; } a; a.f = f;
    unsigned u = a.u;
    u += 0x7FFF + ((u >> 16) & 1);   // RNE
    return (ushort)(u >> 16);
}
__device__ __forceinline__ void gload16(const ushort* g, ushort* l) {
    __builtin_amdgcn_global_load_lds(
        (const __attribute__((address_space(1))) ushort*)g,
        (__attribute__((address_space(3))) ushort*)l, 16, 0, 0);
}
__device__ __forceinline__ unsigned cvtpk(float lo, float hi) {
    unsigned r;
    asm("v_cvt_pk_bf16_f32 %0, %1, %2" : "=v"(r) : "v"(lo), "v"(hi));
    return r;
}
__device__ __forceinline__ void plswap(unsigned &a, unsigned &b) {
    asm("v_permlane32_swap_b32 %0, %1" : "+v"(a), "+v"(b));
}

// ---------------------------------------------------------------------------
// Prepass: fp32 -> bf16 for x and W.  (round-7 exact)
// ---------------------------------------------------------------------------
__global__ __launch_bounds__(256) void cvt_bf16_kernel(
    const float* __restrict__ x, const float* __restrict__ W,
    ushort* __restrict__ xb, ushort* __restrict__ wb)
{
    constexpr int NX = M * C / 4;
    constexpr int NW = 3 * C * C / 4;
    for (int i = blockIdx.x * blockDim.x + threadIdx.x; i < NX + NW;
         i += gridDim.x * blockDim.x) {
        float4 v; ushort* dst; int o;
        if (i < NX) { v = ((const float4*)x)[i]; dst = xb; o = i; }
        else        { v = ((const float4*)W)[i - NX]; dst = wb; o = i - NX; }
        short4v s;
        s.x = (short)f2bf(v.x); s.y = (short)f2bf(v.y);
        s.z = (short)f2bf(v.z); s.w = (short)f2bf(v.w);
        *(short4v*)(dst + (size_t)o * 4) = s;
    }
}

// ---------------------------------------------------------------------------
// QKV GEMM (round-7 EXACT restore -- do not touch; every perturbation
// regressed: R8 +47us, R9 +17us, R12 +40us). bf16 MFMA 128x128 BK=64.
// Epilogue: q rows scaled LOG2E/||q||, k rows 1/||k||, scalar 2B scatter to
// [bh][n pad1664][d]; v -> [bh][d][n pad1664] packed 8B transposed stores.
// ---------------------------------------------------------------------------
__global__ __launch_bounds__(256) void qkv_mfma_kernel(
    const ushort* __restrict__ xb, const ushort* __restrict__ Wb,
    const float* __restrict__ bias, ushort* __restrict__ qg,
    ushort* __restrict__ kg, ushort* __restrict__ vtg)
{
    __shared__ __align__(16) ushort Ab[128][64];
    __shared__ __align__(16) ushort Bb[128][64];

    const int tid = threadIdx.x;
    const int l = tid & 63;
    const int w = tid >> 6;
    const int l15 = l & 15, lg = l >> 4;

    // bijective XCD swizzle (nwg=1764, q=220, r=4)
    const int orig = blockIdx.x;
    const int xcd = orig & 7;
    const int base = (xcd < 4) ? xcd * 221 : 4 * 221 + (xcd - 4) * 220;
    const int wgid = base + (orig >> 3);
    const int mt = wgid / 18;
    const int jt = wgid - mt * 18;
    const int m0 = mt * 128;
    const int j0 = jt * 128;

    const int wr = w >> 1, wc = w & 1;
    const int Rr = l >> 3;
    const int cch = l & 7;

    f32x4 acc[4][4] = {};

    for (int kb = 0; kb < C; kb += 64) {
        __syncthreads();
        #pragma unroll
        for (int i = 0; i < 4; ++i) {
            const int R = (w * 4 + i) * 8 + Rr;
            const int cg = (cch ^ (R & 7)) * 8;
            gload16(xb + (size_t)(m0 + R) * C + kb + cg, &Ab[0][0] + (w * 4 + i) * 512);
            gload16(Wb + (size_t)(j0 + R) * C + kb + cg, &Bb[0][0] + (w * 4 + i) * 512);
        }
        __syncthreads();

        #pragma unroll
        for (int kk = 0; kk < 2; ++kk) {
            bf16x8 af[4], bfr[4];
            #pragma unroll
            for (int t = 0; t < 4; ++t) {
                const int ra = wr * 64 + t * 16 + l15;
                af[t]  = *(const bf16x8*)&Ab[ra][((kk * 4 + lg) ^ (ra & 7)) * 8];
                const int rb = wc * 64 + t * 16 + l15;
                bfr[t] = *(const bf16x8*)&Bb[rb][((kk * 4 + lg) ^ (rb & 7)) * 8];
            }
            #pragma unroll
            for (int mi = 0; mi < 4; ++mi)
                #pragma unroll
                for (int nj = 0; nj < 4; ++nj)
                    acc[mi][nj] = __builtin_amdgcn_mfma_f32_16x16x32_bf16(
                        af[mi], bfr[nj], acc[mi][nj], 0, 0, 0);
        }
    }

    const int sel = jt / 6;
    if (sel < 2) {
        ushort* dst = (sel == 0) ? qg : kg;
        const float scl = (sel == 0) ? LOG2E : 1.f;
        const int jbase = j0 + wc * 64;
        const int h = (jbase - sel * C) >> 6;
        float bbv[4];
        #pragma unroll
        for (int nj = 0; nj < 4; ++nj) bbv[nj] = bias[jbase + nj * 16 + l15];
        #pragma unroll
        for (int mi = 0; mi < 4; ++mi) {
            #pragma unroll
            for (int r = 0; r < 4; ++r) {
                const float v0 = acc[mi][0][r] + bbv[0];
                const float v1 = acc[mi][1][r] + bbv[1];
                const float v2 = acc[mi][2][r] + bbv[2];
                const float v3 = acc[mi][3][r] + bbv[3];
                float ssq = v0*v0 + v1*v1 + v2*v2 + v3*v3;
                ssq += __shfl_xor(ssq, 1); ssq += __shfl_xor(ssq, 2);
                ssq += __shfl_xor(ssq, 4); ssq += __shfl_xor(ssq, 8);
                const float inv = scl / fmaxf(sqrtf(ssq), 1e-12f);
                const int m = m0 + wr * 64 + mi * 16 + lg * 4 + r;
                const int b_ = m / N, n_ = m - b_ * N;
                ushort* o = dst + (((size_t)b_ * H + h) * NP + n_) * D + l15;
                o[0]  = f2bf(v0 * inv);
                o[16] = f2bf(v1 * inv);
                o[32] = f2bf(v2 * inv);
                o[48] = f2bf(v3 * inv);
            }
        }
    } else {
        #pragma unroll
        for (int nj = 0; nj < 4; ++nj) {
            const int jcol = j0 + wc * 64 + nj * 16 + l15;
            const int rem = jcol - 2 * C;
            const int h = rem >> 6, d = rem & 63;
            const float bb = bias[jcol];
            #pragma unroll
            for (int mi = 0; mi < 4; ++mi) {
                const int mb = m0 + wr * 64 + mi * 16 + lg * 4;
                const int b_ = mb / N, n_ = mb - b_ * N;
                short4v o;
                o.x = (short)f2bf(acc[mi][nj][0] + bb);
                o.y = (short)f2bf(acc[mi][nj][1] + bb);
                o.z = (short)f2bf(acc[mi][nj][2] + bb);
                o.w = (short)f2bf(acc[mi][nj][3] + bb);
                *(short4v*)&vtg[(((size_t)b_ * H + h) * D + d) * NP + n_] = o;
            }
        }
    }
}

// ---------------------------------------------------------------------------
// Cosine attention, swapped-QK^T 32x32x16 + in-register softmax (T12).
// KVBLK=128: K tile [128][64] (same row geometry), V = two [64][64] windows
// (staging math identical to KVBLK=64). Halves barrier count (25 -> 13);
// main loop = 12 UNCONDITIONAL iterations (prefetch always legal, no pad
// branch); tile 12 handled in a peeled tail (frag0 = rows 1536..1567 all
// valid, frag1 zeroed, half1 skipped). LDS 64 KiB -> 2 blocks/CU (= today's
// measured residency). Accumulation order unchanged -> bit-identical.
// ---------------------------------------------------------------------------
__global__ __launch_bounds__(256) void attn_kernel(
    const ushort* __restrict__ qg, const ushort* __restrict__ kg,
    const ushort* __restrict__ vtg, float* __restrict__ out)
{
    __shared__ __align__(16) ushort KsB[2][128 * 64];
    __shared__ __align__(16) ushort VtB[2][2][64 * 64];

    const int tid = threadIdx.x;
    const int l   = tid & 63;
    const int w   = tid >> 6;
    const int l31 = l & 31;
    const int hi  = l >> 5;

    const int bid = blockIdx.x;
    const int grp = bid >> 3;                 // 0..155
    const int qt  = grp % QT;
    const int bh  = (bid & 7) + 8 * (grp / QT);

    const ushort* qp  = qg  + (size_t)bh * NP * D;
    const ushort* kp  = kg  + (size_t)bh * NP * D;
    const ushort* vtp = vtg + (size_t)bh * D * NP;

    const int rsub = l >> 3;
    const int cg   = ((l & 7) ^ rsub) << 3;   // pre-swizzled source chunk

    // ---- Q fragments straight from global (logical d-order) ----
    bf16x8 qf[4];
    {
        const ushort* qr = qp + (size_t)(qt * 128 + w * 32 + l31) * D + hi * 8;
        #pragma unroll
        for (int ds = 0; ds < 4; ++ds)
            qf[ds] = *(const bf16x8*)(qr + ds * 16);
    }

    // ---- prologue DMA: tile 0 (K 128 rows; V 2 x 64-col windows) ----
    #pragma unroll
    for (int p = 0; p < 4; ++p) {
        const int rb = p * 32 + w * 8;
        gload16(kp + (size_t)(rb + rsub) * D + cg, KsB[0] + rb * 64);
    }
    #pragma unroll
    for (int h2 = 0; h2 < 2; ++h2)
        #pragma unroll
        for (int p = 0; p < 2; ++p) {
            const int rb = p * 32 + w * 8;
            gload16(vtp + (size_t)(rb + rsub) * NP + h2 * 64 + cg,
                    VtB[0][h2] + rb * 64);
        }
    __syncthreads();

    f32x16 o_acc[2] = {};
    float denom = 0.f;
    int cur = 0;

    for (int kt = 0; kt < KT2 - 1; ++kt) {
        // ---- prefetch tile kt+1 (always exists; no condition) ----
        {
            ushort* Kn = KsB[cur ^ 1];
            #pragma unroll
            for (int p = 0; p < 4; ++p) {
                const int rb = p * 32 + w * 8;
                gload16(kp + (size_t)((kt + 1) * 128 + rb + rsub) * D + cg, Kn + rb * 64);
            }
            #pragma unroll
            for (int h2 = 0; h2 < 2; ++h2)
                #pragma unroll
                for (int p = 0; p < 2; ++p) {
                    const int rb = p * 32 + w * 8;
                    gload16(vtp + (size_t)(rb + rsub) * NP + (kt + 1) * 128 + h2 * 64 + cg,
                            VtB[cur ^ 1][h2] + rb * 64);
                }
        }
        const ushort* Kc = KsB[cur];

        #pragma unroll
        for (int h2 = 0; h2 < 2; ++h2) {
            // ---- S^T = K Q (pre-scaled by log2e), exp2, pack ----
            unsigned pw[16];
            #pragma unroll
            for (int f01 = 0; f01 < 2; ++f01) {
                const int fr = h2 * 2 + f01;
                f32x16 st = {};
                __builtin_amdgcn_s_setprio(1);
                #pragma unroll
                for (int ds = 0; ds < 4; ++ds) {
                    const int krow = fr * 32 + l31;
                    const int ch = (2 * ds + hi) ^ (krow & 7);
                    const bf16x8 kf = *(const bf16x8*)(Kc + krow * 64 + ch * 8);
                    st = __builtin_amdgcn_mfma_f32_32x32x16_bf16(kf, qf[ds], st, 0, 0, 0);
                }
                __builtin_amdgcn_s_setprio(0);
                float p[16];
                #pragma unroll
                for (int r = 0; r < 16; ++r) p[r] = __builtin_amdgcn_exp2f(st[r]);
                const float t =
                    (((p[0]+p[1])+(p[2]+p[3])) + ((p[4]+p[5])+(p[6]+p[7]))) +
                    (((p[8]+p[9])+(p[10]+p[11])) + ((p[12]+p[13])+(p[14]+p[15])));
                denom += t;
                #pragma unroll
                for (int i = 0; i < 8; ++i)
                    pw[f01 * 8 + i] = cvtpk(p[2 * i], p[2 * i + 1]);
            }

            // ---- redistribute (T12 permlane recipe) ----
            #pragma unroll
            for (int q4 = 0; q4 < 4; ++q4) {
                plswap(pw[q4 * 4 + 0], pw[q4 * 4 + 2]);
                plswap(pw[q4 * 4 + 1], pw[q4 * 4 + 3]);
            }

            // ---- O += P V ----
            const ushort* Vc = VtB[cur][h2];
            __builtin_amdgcn_s_setprio(1);
            #pragma unroll
            for (int dt = 0; dt < 2; ++dt) {
                #pragma unroll
                for (int ks = 0; ks < 4; ++ks) {
                    const int vrow = dt * 32 + l31;
                    const int ch = (2 * ks + hi) ^ (vrow & 7);
                    const bf16x8 vf = *(const bf16x8*)(Vc + vrow * 64 + ch * 8);
                    union { unsigned u[4]; bf16x8 v; } A;
                    A.u[0] = pw[ks * 4 + 0]; A.u[1] = pw[ks * 4 + 1];
                    A.u[2] = pw[ks * 4 + 2]; A.u[3] = pw[ks * 4 + 3];
                    o_acc[dt] = __builtin_amdgcn_mfma_f32_32x32x16_bf16(
                        A.v, vf, o_acc[dt], 0, 0, 0);
                }
            }
            __builtin_amdgcn_s_setprio(0);
        }

        __syncthreads();   // drains prefetch DMA; all waves done with cur
        cur ^= 1;
    }

    // ---- peeled tail: tile 12 (cur==0), half 0 only; frag1 = pad ----
    {
        const ushort* Kc = KsB[cur];
        unsigned pw[16];
        {
            f32x16 st = {};
            __builtin_amdgcn_s_setprio(1);
            #pragma unroll
            for (int ds = 0; ds < 4; ++ds) {
                const int krow = l31;                       // fr = 0
                const int ch = (2 * ds + hi) ^ (krow & 7);
                const bf16x8 kf = *(const bf16x8*)(Kc + krow * 64 + ch * 8);
                st = __builtin_amdgcn_mfma_f32_32x32x16_bf16(kf, qf[ds], st, 0, 0, 0);
            }
            __builtin_amdgcn_s_setprio(0);
            float p[16];
            #pragma unroll
            for (int r = 0; r < 16; ++r) p[r] = __builtin_amdgcn_exp2f(st[r]);
            const float t =
                (((p[0]+p[1])+(p[2]+p[3])) + ((p[4]+p[5])+(p[6]+p[7]))) +
                (((p[8]+p[9])+(p[10]+p[11])) + ((p[12]+p[13])+(p[14]+p[15])));
            denom += t;
            #pragma unroll
            for (int i = 0; i < 8; ++i)
                pw[i] = cvtpk(p[2 * i], p[2 * i + 1]);
        }
        #pragma unroll
        for (int i = 0; i < 8; ++i) pw[8 + i] = 0;          // rows 1568..1599
        #pragma unroll
        for (int q4 = 0; q4 < 4; ++q4) {
            plswap(pw[q4 * 4 + 0], pw[q4 * 4 + 2]);
            plswap(pw[q4 * 4 + 1], pw[q4 * 4 + 3]);
        }
        const ushort* Vc = VtB[cur][0];
        __builtin_amdgcn_s_setprio(1);
        #pragma unroll
        for (int dt = 0; dt < 2; ++dt) {
            #pragma unroll
            for (int ks = 0; ks < 4; ++ks) {
                const int vrow = dt * 32 + l31;
                const int ch = (2 * ks + hi) ^ (vrow & 7);
                const bf16x8 vf = *(const bf16x8*)(Vc + vrow * 64 + ch * 8);
                union { unsigned u[4]; bf16x8 v; } A;
                A.u[0] = pw[ks * 4 + 0]; A.u[1] = pw[ks * 4 + 1];
                A.u[2] = pw[ks * 4 + 2]; A.u[3] = pw[ks * 4 + 3];
                o_acc[dt] = __builtin_amdgcn_mfma_f32_32x32x16_bf16(
                    A.v, vf, o_acc[dt], 0, 0, 0);
            }
        }
        __builtin_amdgcn_s_setprio(0);
    }

    // ---- epilogue: reduce denom, broadcast via (freed) K LDS ----
    denom += __shfl_xor(denom, 32);
    __syncthreads();                       // all tail reads of KsB done
    float* dn = (float*)&KsB[0][0];
    if (hi == 0) dn[w * 32 + l31] = 1.f / denom;
    __syncthreads();

    const int b_ = bh / H;
    const int h_ = bh % H;
    #pragma unroll
    for (int g = 0; g < 4; ++g) {
        const f32x4 inv4 = *(const f32x4*)&dn[w * 32 + g * 8 + hi * 4];
        #pragma unroll
        for (int r3 = 0; r3 < 4; ++r3) {
            const int n = qt * 128 + w * 32 + g * 8 + hi * 4 + r3;
            if (n < N) {
                const float iv = inv4[r3];
                #pragma unroll
                for (int dt = 0; dt < 2; ++dt)
                    out[((size_t)b_ * N + n) * C + (h_ << 6) + dt * 32 + l31] =
                        o_acc[dt][g * 4 + r3] * iv;
            }
        }
    }
}

extern "C" void kernel_launch(void* const* d_in, const int* in_sizes, int n_in,
                              void* d_out, int out_size, void* d_ws, size_t ws_size,
                              hipStream_t stream) {
    const float* x  = (const float*)d_in[0];
    const float* Wq = (const float*)d_in[1];
    const float* bq = (const float*)d_in[2];
    float* out = (float*)d_out;
    ushort* ws = (ushort*)d_ws;

    ushort* xb  = ws + OFF_XB;
    ushort* wb  = ws + OFF_WB;
    ushort* qg  = ws + OFF_Q;
    ushort* kg  = ws + OFF_K;
    ushort* vtg = ws + OFF_VT;

    cvt_bf16_kernel<<<2048, 256, 0, stream>>>(x, Wq, xb, wb);
    qkv_mfma_kernel<<<(M / 128) * (3 * C / 128), 256, 0, stream>>>(xb, wb, bq, qg, kg, vtg);
    attn_kernel<<<QT * B * H, 256, 0, stream>>>(qg, kg, vtg, out);
}

// Round 14
// 171.980 us; speedup vs baseline: 1.2440x; 1.0191x over previous
//
#include <hip/hip_runtime.h>

typedef __attribute__((ext_vector_type(8))) short bf16x8;
typedef __attribute__((ext_vector_type(4))) float f32x4;
typedef __attribute__((ext_vector_type(16))) float f32x16;
typedef __attribute__((ext_vector_type(4))) short short4v;

namespace {
constexpr int B = 8;
constexpr int N = 1568;
constexpr int NP = 1664;                 // padded rows: 13 q-tiles x 128
constexpr int C = 768;
constexpr int H = 12;
constexpr int D = 64;
constexpr int M = B * N;                 // 12544
constexpr int NT = 25;                   // kv tiles of 64
constexpr int QT = 13;                   // q tiles of 128
constexpr size_t QKP = (size_t)B * H * NP * D;
// ws layout (ushort): xb | Wb | q | k | vT
constexpr size_t OFF_XB = 0;
constexpr size_t OFF_WB = OFF_XB + (size_t)M * C;
constexpr size_t OFF_Q  = OFF_WB + (size_t)3 * C * C;
constexpr size_t OFF_K  = OFF_Q + QKP;
constexpr size_t OFF_VT = OFF_K + QKP;
constexpr float LOG2E = 1.44269504088896f;
}

__device__ __forceinline__ ushort f2bf(float f) {
    union { float f; unsigned u; } a; a.f = f;
    unsigned u = a.u;
    u += 0x7FFF + ((u >> 16) & 1);   // RNE
    return (ushort)(u >> 16);
}
__device__ __forceinline__ void gload16(const ushort* g, ushort* l) {
    __builtin_amdgcn_global_load_lds(
        (const __attribute__((address_space(1))) ushort*)g,
        (__attribute__((address_space(3))) ushort*)l, 16, 0, 0);
}
__device__ __forceinline__ unsigned cvtpk(float lo, float hi) {
    unsigned r;
    asm("v_cvt_pk_bf16_f32 %0, %1, %2" : "=v"(r) : "v"(lo), "v"(hi));
    return r;
}
__device__ __forceinline__ void plswap(unsigned &a, unsigned &b) {
    asm("v_permlane32_swap_b32 %0, %1" : "+v"(a), "+v"(b));
}

// ---------------------------------------------------------------------------
// Prepass: fp32 -> bf16 for x and W.
// ---------------------------------------------------------------------------
__global__ __launch_bounds__(256) void cvt_bf16_kernel(
    const float* __restrict__ x, const float* __restrict__ W,
    ushort* __restrict__ xb, ushort* __restrict__ wb)
{
    constexpr int NX = M * C / 4;
    constexpr int NW = 3 * C * C / 4;
    for (int i = blockIdx.x * blockDim.x + threadIdx.x; i < NX + NW;
         i += gridDim.x * blockDim.x) {
        float4 v; ushort* dst; int o;
        if (i < NX) { v = ((const float4*)x)[i]; dst = xb; o = i; }
        else        { v = ((const float4*)W)[i - NX]; dst = wb; o = i - NX; }
        short4v s;
        s.x = (short)f2bf(v.x); s.y = (short)f2bf(v.y);
        s.z = (short)f2bf(v.z); s.w = (short)f2bf(v.w);
        *(short4v*)(dst + (size_t)o * 4) = s;
    }
}

// ---------------------------------------------------------------------------
// QKV GEMM (round-7 exact -- empirical minimum; every perturbation
// regressed: R8 +55us, R9 +17us, R12 +42us). bf16 MFMA 128x128 BK=64.
// Epilogue: q rows scaled by LOG2E/||q|| (exp2 fold), k rows by 1/||k||;
// bf16 scatter to [bh][n pad1664][d]; v -> [bh][d][n pad1664] packed 8B
// transposed stores.
// ---------------------------------------------------------------------------
__global__ __launch_bounds__(256) void qkv_mfma_kernel(
    const ushort* __restrict__ xb, const ushort* __restrict__ Wb,
    const float* __restrict__ bias, ushort* __restrict__ qg,
    ushort* __restrict__ kg, ushort* __restrict__ vtg)
{
    __shared__ __align__(16) ushort Ab[128][64];
    __shared__ __align__(16) ushort Bb[128][64];

    const int tid = threadIdx.x;
    const int l = tid & 63;
    const int w = tid >> 6;
    const int l15 = l & 15, lg = l >> 4;

    // bijective XCD swizzle (nwg=1764, q=220, r=4)
    const int orig = blockIdx.x;
    const int xcd = orig & 7;
    const int base = (xcd < 4) ? xcd * 221 : 4 * 221 + (xcd - 4) * 220;
    const int wgid = base + (orig >> 3);
    const int mt = wgid / 18;
    const int jt = wgid - mt * 18;
    const int m0 = mt * 128;
    const int j0 = jt * 128;

    const int wr = w >> 1, wc = w & 1;
    const int Rr = l >> 3;
    const int cch = l & 7;

    f32x4 acc[4][4] = {};

    for (int kb = 0; kb < C; kb += 64) {
        __syncthreads();
        #pragma unroll
        for (int i = 0; i < 4; ++i) {
            const int R = (w * 4 + i) * 8 + Rr;
            const int cg = (cch ^ (R & 7)) * 8;
            gload16(xb + (size_t)(m0 + R) * C + kb + cg, &Ab[0][0] + (w * 4 + i) * 512);
            gload16(Wb + (size_t)(j0 + R) * C + kb + cg, &Bb[0][0] + (w * 4 + i) * 512);
        }
        __syncthreads();

        #pragma unroll
        for (int kk = 0; kk < 2; ++kk) {
            bf16x8 af[4], bfr[4];
            #pragma unroll
            for (int t = 0; t < 4; ++t) {
                const int ra = wr * 64 + t * 16 + l15;
                af[t]  = *(const bf16x8*)&Ab[ra][((kk * 4 + lg) ^ (ra & 7)) * 8];
                const int rb = wc * 64 + t * 16 + l15;
                bfr[t] = *(const bf16x8*)&Bb[rb][((kk * 4 + lg) ^ (rb & 7)) * 8];
            }
            #pragma unroll
            for (int mi = 0; mi < 4; ++mi)
                #pragma unroll
                for (int nj = 0; nj < 4; ++nj)
                    acc[mi][nj] = __builtin_amdgcn_mfma_f32_16x16x32_bf16(
                        af[mi], bfr[nj], acc[mi][nj], 0, 0, 0);
        }
    }

    const int sel = jt / 6;
    if (sel < 2) {
        ushort* dst = (sel == 0) ? qg : kg;
        const float scl = (sel == 0) ? LOG2E : 1.f;
        const int jbase = j0 + wc * 64;
        const int h = (jbase - sel * C) >> 6;
        float bbv[4];
        #pragma unroll
        for (int nj = 0; nj < 4; ++nj) bbv[nj] = bias[jbase + nj * 16 + l15];
        #pragma unroll
        for (int mi = 0; mi < 4; ++mi) {
            #pragma unroll
            for (int r = 0; r < 4; ++r) {
                const float v0 = acc[mi][0][r] + bbv[0];
                const float v1 = acc[mi][1][r] + bbv[1];
                const float v2 = acc[mi][2][r] + bbv[2];
                const float v3 = acc[mi][3][r] + bbv[3];
                float ssq = v0*v0 + v1*v1 + v2*v2 + v3*v3;
                ssq += __shfl_xor(ssq, 1); ssq += __shfl_xor(ssq, 2);
                ssq += __shfl_xor(ssq, 4); ssq += __shfl_xor(ssq, 8);
                const float inv = scl / fmaxf(sqrtf(ssq), 1e-12f);
                const int m = m0 + wr * 64 + mi * 16 + lg * 4 + r;
                const int b_ = m / N, n_ = m - b_ * N;
                ushort* o = dst + (((size_t)b_ * H + h) * NP + n_) * D + l15;
                o[0]  = f2bf(v0 * inv);
                o[16] = f2bf(v1 * inv);
                o[32] = f2bf(v2 * inv);
                o[48] = f2bf(v3 * inv);
            }
        }
    } else {
        #pragma unroll
        for (int nj = 0; nj < 4; ++nj) {
            const int jcol = j0 + wc * 64 + nj * 16 + l15;
            const int rem = jcol - 2 * C;
            const int h = rem >> 6, d = rem & 63;
            const float bb = bias[jcol];
            #pragma unroll
            for (int mi = 0; mi < 4; ++mi) {
                const int mb = m0 + wr * 64 + mi * 16 + lg * 4;
                const int b_ = mb / N, n_ = mb - b_ * N;
                short4v o;
                o.x = (short)f2bf(acc[mi][nj][0] + bb);
                o.y = (short)f2bf(acc[mi][nj][1] + bb);
                o.z = (short)f2bf(acc[mi][nj][2] + bb);
                o.w = (short)f2bf(acc[mi][nj][3] + bb);
                *(short4v*)&vtg[(((size_t)b_ * H + h) * D + d) * NP + n_] = o;
            }
        }
    }
}

// ---------------------------------------------------------------------------
// Cosine attention (round-7 exact): swapped-QK^T 32x32x16 + in-register
// softmax (T12). Q fragments straight from global (no Q LDS). K/V
// double-buffered in LDS via global_load_lds (32 KiB). exp2 on pre-scaled
// scores. setprio around MFMA clusters. One barrier per kv tile.
// ---------------------------------------------------------------------------
__global__ __launch_bounds__(256) void attn_kernel(
    const ushort* __restrict__ qg, const ushort* __restrict__ kg,
    const ushort* __restrict__ vtg, float* __restrict__ out)
{
    __shared__ __align__(16) ushort KsB[2][64 * 64];
    __shared__ __align__(16) ushort VtB[2][64 * 64];

    const int tid = threadIdx.x;
    const int l   = tid & 63;
    const int w   = tid >> 6;
    const int l31 = l & 31;
    const int hi  = l >> 5;

    const int bid = blockIdx.x;
    const int grp = bid >> 3;                 // 0..155
    const int qt  = grp % QT;
    const int bh  = (bid & 7) + 8 * (grp / QT);

    const ushort* qp  = qg  + (size_t)bh * NP * D;
    const ushort* kp  = kg  + (size_t)bh * NP * D;
    const ushort* vtp = vtg + (size_t)bh * D * NP;

    const int rsub = l >> 3;
    const int cg   = ((l & 7) ^ rsub) << 3;   // pre-swizzled source chunk

    // ---- Q fragments straight from global (logical d-order) ----
    bf16x8 qf[4];
    {
        const ushort* qr = qp + (size_t)(qt * 128 + w * 32 + l31) * D + hi * 8;
        #pragma unroll
        for (int ds = 0; ds < 4; ++ds)
            qf[ds] = *(const bf16x8*)(qr + ds * 16);
    }

    // ---- prologue DMA: K/V tile 0 ----
    #pragma unroll
    for (int p = 0; p < 2; ++p) {
        const int rb = p * 32 + w * 8;
        gload16(kp + (size_t)(rb + rsub) * D + cg, KsB[0] + rb * 64);
        gload16(vtp + (size_t)(rb + rsub) * NP + cg, VtB[0] + rb * 64);
    }
    __syncthreads();

    f32x16 o_acc[2] = {};
    float denom = 0.f;
    int cur = 0;

    for (int kt = 0; kt < NT; ++kt) {
        if (kt + 1 < NT) {
            ushort* Kn = KsB[cur ^ 1];
            ushort* Vn = VtB[cur ^ 1];
            #pragma unroll
            for (int p = 0; p < 2; ++p) {
                const int rb = p * 32 + w * 8;
                gload16(kp + (size_t)((kt + 1) * 64 + rb + rsub) * D + cg, Kn + rb * 64);
                gload16(vtp + (size_t)(rb + rsub) * NP + (kt + 1) * 64 + cg, Vn + rb * 64);
            }
        }
        const ushort* Kc = KsB[cur];
        const ushort* Vc = VtB[cur];

        // ---- S^T = K Q (scores pre-scaled by log2e), exp2, pack ----
        unsigned pw[16];
        #pragma unroll
        for (int f = 0; f < 2; ++f) {
            if (f == 1 && kt == NT - 1) {
                #pragma unroll
                for (int i = 0; i < 8; ++i) pw[8 + i] = 0;   // pad kv rows
            } else {
                f32x16 st = {};
                __builtin_amdgcn_s_setprio(1);
                #pragma unroll
                for (int ds = 0; ds < 4; ++ds) {
                    const int krow = f * 32 + l31;
                    const int ch = (2 * ds + hi) ^ (krow & 7);
                    const bf16x8 kf = *(const bf16x8*)(Kc + krow * 64 + ch * 8);
                    st = __builtin_amdgcn_mfma_f32_32x32x16_bf16(kf, qf[ds], st, 0, 0, 0);
                }
                __builtin_amdgcn_s_setprio(0);
                float p[16];
                #pragma unroll
                for (int r = 0; r < 16; ++r) p[r] = __builtin_amdgcn_exp2f(st[r]);
                const float t =
                    (((p[0]+p[1])+(p[2]+p[3])) + ((p[4]+p[5])+(p[6]+p[7]))) +
                    (((p[8]+p[9])+(p[10]+p[11])) + ((p[12]+p[13])+(p[14]+p[15])));
                denom += t;
                #pragma unroll
                for (int i = 0; i < 8; ++i)
                    pw[f * 8 + i] = cvtpk(p[2 * i], p[2 * i + 1]);
            }
        }

        // ---- redistribute: words -> PV A-fragments (T12 permlane recipe) ----
        #pragma unroll
        for (int q4 = 0; q4 < 4; ++q4) {
            plswap(pw[q4 * 4 + 0], pw[q4 * 4 + 2]);
            plswap(pw[q4 * 4 + 1], pw[q4 * 4 + 3]);
        }

        // ---- O += P V ----
        __builtin_amdgcn_s_setprio(1);
        #pragma unroll
        for (int dt = 0; dt < 2; ++dt) {
            #pragma unroll
            for (int ks = 0; ks < 4; ++ks) {
                const int vrow = dt * 32 + l31;
                const int ch = (2 * ks + hi) ^ (vrow & 7);
                const bf16x8 vf = *(const bf16x8*)(Vc + vrow * 64 + ch * 8);
                union { unsigned u[4]; bf16x8 v; } A;
                A.u[0] = pw[ks * 4 + 0]; A.u[1] = pw[ks * 4 + 1];
                A.u[2] = pw[ks * 4 + 2]; A.u[3] = pw[ks * 4 + 3];
                o_acc[dt] = __builtin_amdgcn_mfma_f32_32x32x16_bf16(
                    A.v, vf, o_acc[dt], 0, 0, 0);
            }
        }
        __builtin_amdgcn_s_setprio(0);

        __syncthreads();   // drains next-tile DMA; all waves done with cur
        cur ^= 1;
    }

    // ---- epilogue: reduce denom, broadcast via (freed) K LDS ----
    denom += __shfl_xor(denom, 32);
    float* dn = (float*)&KsB[0][0];
    if (hi == 0) dn[w * 32 + l31] = 1.f / denom;
    __syncthreads();

    const int b_ = bh / H;
    const int h_ = bh % H;
    #pragma unroll
    for (int g = 0; g < 4; ++g) {
        const f32x4 inv4 = *(const f32x4*)&dn[w * 32 + g * 8 + hi * 4];
        #pragma unroll
        for (int r3 = 0; r3 < 4; ++r3) {
            const int n = qt * 128 + w * 32 + g * 8 + hi * 4 + r3;
            if (n < N) {
                const float iv = inv4[r3];
                #pragma unroll
                for (int dt = 0; dt < 2; ++dt)
                    out[((size_t)b_ * N + n) * C + (h_ << 6) + dt * 32 + l31] =
                        o_acc[dt][g * 4 + r3] * iv;
            }
        }
    }
}

extern "C" void kernel_launch(void* const* d_in, const int* in_sizes, int n_in,
                              void* d_out, int out_size, void* d_ws, size_t ws_size,
                              hipStream_t stream) {
    const float* x  = (const float*)d_in[0];
    const float* Wq = (const float*)d_in[1];
    const float* bq = (const float*)d_in[2];
    float* out = (float*)d_out;
    ushort* ws = (ushort*)d_ws;

    ushort* xb  = ws + OFF_XB;
    ushort* wb  = ws + OFF_WB;
    ushort* qg  = ws + OFF_Q;
    ushort* kg  = ws + OFF_K;
    ushort* vtg = ws + OFF_VT;

    cvt_bf16_kernel<<<2048, 256, 0, stream>>>(x, Wq, xb, wb);
    qkv_mfma_kernel<<<(M / 128) * (3 * C / 128), 256, 0, stream>>>(xb, wb, bq, qg, kg, vtg);
    attn_kernel<<<QT * B * H, 256, 0, stream>>>(qg, kg, vtg, out);
}